// Round 7
// baseline (229.913 us; speedup 1.0000x reference)
//
#include <hip/hip_runtime.h>

#define NG 16384
#define NT 200
#define FREEZE_EPS 3e-4f

// DPP cross-lane (VALU pipe), all within aligned 8-lane octets
#define DPPF(v, ctrl) __int_as_float(__builtin_amdgcn_update_dpp( \
    0, __float_as_int(v), (ctrl), 0xF, 0xF, true))
#define QP1(v) DPPF(v, 0xB1)   // src lane ^ 1
#define QP2(v) DPPF(v, 0x4E)   // src lane ^ 2
#define RHM(v) DPPF(v, 0x141)  // src lane ^ 7 (row_half_mirror)

__device__ __forceinline__ float allred8(float v) {
  v += QP1(v); v += QP2(v); v += RHM(v); return v;
}
__device__ __forceinline__ float allmax8(float v) {
  v = fmaxf(v, QP1(v)); v = fmaxf(v, QP2(v)); v = fmaxf(v, RHM(v)); return v;
}
// reduce-scatter butterfly: lane r ends with sum_k F[r][k]*val[k].
// Fd[s] = F[r^kd[s]][r], kd = [0,1,2,3,7,6,5,4].
__device__ __forceinline__ float matvec8(const float* __restrict__ Fd, float val) {
  float c0 = Fd[0]*val, c1 = Fd[1]*val, c2 = Fd[2]*val, c3 = Fd[3]*val;
  float c4 = Fd[4]*val, c5 = Fd[5]*val, c6 = Fd[6]*val, c7 = Fd[7]*val;
  float a0 = c0 + RHM(c4), a1 = c1 + RHM(c5), a2 = c2 + RHM(c6), a3 = c3 + RHM(c7);
  float b0 = a0 + QP2(a2), b1 = a1 + QP2(a3);
  return b0 + QP1(b1);
}

__global__ __launch_bounds__(256, 1)
void kf_kernel(const float* __restrict__ x,
               const float* __restrict__ m0,
               const float* __restrict__ P0,
               const float* __restrict__ Fm,
               const float* __restrict__ Qm,
               const float* __restrict__ Hm,
               const float* __restrict__ Rm,
               float* __restrict__ out) {
  const int tid = threadIdx.x;
  const int r   = tid & 7;
  const int g   = blockIdx.x * 32 + (tid >> 3);

  // ---- per-lane xor-indexed parameter tables ----
  constexpr int kD[8] = {0, 1, 2, 3, 7, 6, 5, 4};
  float Fd[8];   // F[r^kd[s]][r]
#pragma unroll
  for (int s = 0; s < 8; ++s) Fd[s] = Fm[((r ^ kD[s]) << 3) | r];
  float Frt[8], Qt[8], Hd0[8], Hd1[8];
#pragma unroll
  for (int c = 0; c < 8; ++c) {
    Frt[c] = Fm[(r << 3) | (r ^ c)];
    Qt[c]  = Qm[(r << 3) | (r ^ c)];
    Hd0[c] = Hm[r ^ c];
    Hd1[c] = Hm[8 + (r ^ c)];
  }
  const float R00 = Rm[0], R01 = Rm[1], R11 = Rm[3];

  // ---- Fde[dl][c] = F[r^dl][r^c], built once via DPP chains ----
  float Fde[8][8];
  {
    float t1[8], t2[8], t3[8], tt[8];
#pragma unroll
    for (int c = 0; c < 8; ++c) Fde[0][c] = Frt[c];
#pragma unroll
    for (int c = 0; c < 8; ++c) t1[c] = QP1(Frt[c]);
#pragma unroll
    for (int c = 0; c < 8; ++c) Fde[1][c] = t1[1 ^ c];
#pragma unroll
    for (int c = 0; c < 8; ++c) t2[c] = QP2(Frt[c]);
#pragma unroll
    for (int c = 0; c < 8; ++c) Fde[2][c] = t2[2 ^ c];
#pragma unroll
    for (int c = 0; c < 8; ++c) t3[c] = QP2(t1[c]);
#pragma unroll
    for (int c = 0; c < 8; ++c) Fde[3][c] = t3[3 ^ c];
#pragma unroll
    for (int c = 0; c < 8; ++c) tt[c] = RHM(Frt[c]);
#pragma unroll
    for (int c = 0; c < 8; ++c) Fde[7][c] = tt[7 ^ c];
#pragma unroll
    for (int c = 0; c < 8; ++c) tt[c] = RHM(t1[c]);
#pragma unroll
    for (int c = 0; c < 8; ++c) Fde[6][c] = tt[6 ^ c];
#pragma unroll
    for (int c = 0; c < 8; ++c) tt[c] = RHM(t2[c]);
#pragma unroll
    for (int c = 0; c < 8; ++c) Fde[5][c] = tt[5 ^ c];
#pragma unroll
    for (int c = 0; c < 8; ++c) tt[c] = RHM(t3[c]);
#pragma unroll
    for (int c = 0; c < 8; ++c) Fde[4][c] = tt[4 ^ c];
  }

  // ---- per-group state: lane r holds m[r] and P~[d] = P[r][r^d] ----
  float m = m0[(size_t)g * 8 + r];
  float Pt[8];
#pragma unroll
  for (int d = 0; d < 8; ++d)
    Pt[d] = P0[(size_t)g * 64 + (r << 3) + (r ^ d)];

  const float* xg = x + (size_t)g * NT * 2;
  float* mo = out + (size_t)g * NT * 2;
  float* co = out + (size_t)NG * NT * 2 + (size_t)g * NT * 4;

  float kt0 = 0.f, kt1 = 0.f, s00 = 0.f, s01 = 0.f, s11 = 0.f;
  bool frozen = false;

  // ---- x double-buffer: 4-step batches (two float4 per batch) ----
  float4 xa = *reinterpret_cast<const float4*>(xg);
  float4 xb = *reinterpret_cast<const float4*>(xg + 4);
  float4 na = *reinterpret_cast<const float4*>(xg + 8);
  float4 nb = *reinterpret_cast<const float4*>(xg + 12);

  int tb = 0;
  bool wfrozen = false;

  // ================= Phase 1: Riccati (until wave-uniform freeze) ==========
#pragma unroll 1
  for (; tb < NT && !wfrozen; tb += 4) {
#pragma unroll
    for (int j = 0; j < 4; ++j) {
      const int t = tb + j;
      const float x0 = (j == 0) ? xa.x : (j == 1) ? xa.z : (j == 2) ? xb.x : xb.z;
      const float x1 = (j == 0) ? xa.y : (j == 1) ? xa.w : (j == 2) ? xb.y : xb.w;

      float mm0 = allred8(Hd0[0] * m);
      float mm1 = allred8(Hd1[0] * m);

      if (!frozen) {
        float a0 = fmaf(Hd0[1], Pt[1], Hd0[0] * Pt[0]);
        float a1 = fmaf(Hd0[3], Pt[3], Hd0[2] * Pt[2]);
        float a2 = fmaf(Hd0[5], Pt[5], Hd0[4] * Pt[4]);
        float a3 = fmaf(Hd0[7], Pt[7], Hd0[6] * Pt[6]);
        const float hp0 = (a0 + a1) + (a2 + a3);
        float b0 = fmaf(Hd1[1], Pt[1], Hd1[0] * Pt[0]);
        float b1 = fmaf(Hd1[3], Pt[3], Hd1[2] * Pt[2]);
        float b2 = fmaf(Hd1[5], Pt[5], Hd1[4] * Pt[4]);
        float b3 = fmaf(Hd1[7], Pt[7], Hd1[6] * Pt[6]);
        const float hp1 = (b0 + b1) + (b2 + b3);

        s00 = R00 + allred8(hp0 * Hd0[0]);
        s01 = R01 + allred8(hp0 * Hd1[0]);
        s11 = R11 + allred8(hp1 * Hd1[0]);
        const float det  = fmaf(s00, s11, -(s01 * s01));
        const float rdet = 1.0f / det;
        const float i00 = s11 * rdet, i01 = -s01 * rdet, i11 = s00 * rdet;
        kt0 = i00 * hp0 + i01 * hp1;
        kt1 = i01 * hp0 + i11 * hp1;

        float G0[8], G1[8];
        G0[0] = hp0;        G1[0] = hp1;
        G0[1] = QP1(hp0);   G1[1] = QP1(hp1);
        G0[2] = QP2(hp0);   G1[2] = QP2(hp1);
        G0[3] = QP2(G0[1]); G1[3] = QP2(G1[1]);
        G0[7] = RHM(hp0);   G1[7] = RHM(hp1);
        G0[6] = RHM(G0[1]); G1[6] = RHM(G1[1]);
        G0[5] = RHM(G0[2]); G1[5] = RHM(G1[2]);
        G0[4] = RHM(G0[3]); G1[4] = RHM(G1[3]);

        float Pu[8];
#pragma unroll
        for (int d = 0; d < 8; ++d)
          Pu[d] = Pt[d] - kt0 * G0[d] - kt1 * G1[d];

        float V[8];
#pragma unroll
        for (int dl = 0; dl < 8; ++dl) {
          float u0 = fmaf(Pu[1], Fde[dl][1], Pu[0] * Fde[dl][0]);
          float u1 = fmaf(Pu[3], Fde[dl][3], Pu[2] * Fde[dl][2]);
          float u2 = fmaf(Pu[5], Fde[dl][5], Pu[4] * Fde[dl][4]);
          float u3 = fmaf(Pu[7], Fde[dl][7], Pu[6] * Fde[dl][6]);
          V[dl] = (u0 + u1) + (u2 + u3);
        }

        float Pn[8], A1[8], A2[8], A3[8], T[8];
#pragma unroll
        for (int d = 0; d < 8; ++d) Pn[d] = fmaf(Frt[0], V[d], Qt[d]);
#pragma unroll
        for (int c = 0; c < 8; ++c) A1[c] = QP1(V[c]);
#pragma unroll
        for (int d = 0; d < 8; ++d) Pn[d] = fmaf(Frt[1], A1[1 ^ d], Pn[d]);
#pragma unroll
        for (int c = 0; c < 8; ++c) A2[c] = QP2(V[c]);
#pragma unroll
        for (int d = 0; d < 8; ++d) Pn[d] = fmaf(Frt[2], A2[2 ^ d], Pn[d]);
#pragma unroll
        for (int c = 0; c < 8; ++c) A3[c] = QP2(A1[c]);
#pragma unroll
        for (int d = 0; d < 8; ++d) Pn[d] = fmaf(Frt[3], A3[3 ^ d], Pn[d]);
#pragma unroll
        for (int c = 0; c < 8; ++c) T[c] = RHM(V[c]);
#pragma unroll
        for (int d = 0; d < 8; ++d) Pn[d] = fmaf(Frt[7], T[7 ^ d], Pn[d]);
#pragma unroll
        for (int c = 0; c < 8; ++c) T[c] = RHM(A1[c]);
#pragma unroll
        for (int d = 0; d < 8; ++d) Pn[d] = fmaf(Frt[6], T[6 ^ d], Pn[d]);
#pragma unroll
        for (int c = 0; c < 8; ++c) T[c] = RHM(A2[c]);
#pragma unroll
        for (int d = 0; d < 8; ++d) Pn[d] = fmaf(Frt[5], T[5 ^ d], Pn[d]);
#pragma unroll
        for (int c = 0; c < 8; ++c) T[c] = RHM(A3[c]);
#pragma unroll
        for (int d = 0; d < 8; ++d) Pn[d] = fmaf(Frt[4], T[4 ^ d], Pn[d]);

        if (t & 1) {
          float dmax = 0.f;
#pragma unroll
          for (int c = 0; c < 8; ++c) dmax = fmaxf(dmax, fabsf(Pn[c] - Pt[c]));
          frozen = allmax8(dmax) < FREEZE_EPS;
        }
#pragma unroll
        for (int c = 0; c < 8; ++c) Pt[c] = Pn[c];
      }

      if (r == 0) *reinterpret_cast<float2*>(mo + 2 * t) = make_float2(mm0, mm1);
      if (r == 1) *reinterpret_cast<float4*>(co + 4 * t) = make_float4(s00, s01, s01, s11);

      const float y0 = x0 - mm0, y1 = x1 - mm1;
      const float mu = fmaf(kt0, y0, fmaf(kt1, y1, m));
      m = matvec8(Fd, mu);
    }
    xa = na; xb = nb;
    int tf = tb + 8; if (tf > NT - 4) tf = NT - 4;
    na = *reinterpret_cast<const float4*>(xg + 2 * tf);
    nb = *reinterpret_cast<const float4*>(xg + 2 * tf + 4);
    wfrozen = __all(frozen);
  }

  // ================= Phase 2: steady-state linear filter ====================
  if (tb < NT) {
    // mm for first steady step
    float mm0 = allred8(Hd0[0] * m);
    float mm1 = allred8(Hd1[0] * m);
    // HF rows (per-lane, all-local): HF_i[r] = sum_e H_i[r^e] * F[r^e][r]
    float u0 = fmaf(Hd0[1], Fde[1][0], Hd0[0] * Fde[0][0]);
    float u1 = fmaf(Hd0[3], Fde[3][0], Hd0[2] * Fde[2][0]);
    float u2 = fmaf(Hd0[5], Fde[5][0], Hd0[4] * Fde[4][0]);
    float u3 = fmaf(Hd0[7], Fde[7][0], Hd0[6] * Fde[6][0]);
    const float HF0r = (u0 + u1) + (u2 + u3);
    float w0 = fmaf(Hd1[1], Fde[1][0], Hd1[0] * Fde[0][0]);
    float w1 = fmaf(Hd1[3], Fde[3][0], Hd1[2] * Fde[2][0]);
    float w2 = fmaf(Hd1[5], Fde[5][0], Hd1[4] * Fde[4][0]);
    float w3 = fmaf(Hd1[7], Fde[7][0], Hd1[6] * Fde[6][0]);
    const float HF1r = (w0 + w1) + (w2 + w3);
    // HFK (octet-uniform 2x2) and FK columns (per-lane)
    const float hfk00 = allred8(HF0r * kt0), hfk01 = allred8(HF0r * kt1);
    const float hfk10 = allred8(HF1r * kt0), hfk11 = allred8(HF1r * kt1);
    const float fk0 = matvec8(Fd, kt0), fk1 = matvec8(Fd, kt1);

    // constant covariance blast: lane-strided, 128B contiguous per octet
    const float4 cv = make_float4(s00, s01, s01, s11);
#pragma unroll 1
    for (int k2 = tb + r; k2 < NT; k2 += 8)
      *reinterpret_cast<float4*>(co + 4 * k2) = cv;

#pragma unroll 1
    for (; tb < NT; tb += 4) {
      float2 b0, b1, b2, b3;
#pragma unroll
      for (int j = 0; j < 4; ++j) {
        const float x0 = (j == 0) ? xa.x : (j == 1) ? xa.z : (j == 2) ? xb.x : xb.z;
        const float x1 = (j == 0) ? xa.y : (j == 1) ? xa.w : (j == 2) ? xb.y : xb.w;
        const float y0 = x0 - mm0, y1 = x1 - mm1;
        if (j == 0) b0 = make_float2(mm0, mm1);
        else if (j == 1) b1 = make_float2(mm0, mm1);
        else if (j == 2) b2 = make_float2(mm0, mm1);
        else b3 = make_float2(mm0, mm1);
        const float wa = allred8(HF0r * m);   // (HF m)[0]
        const float wb = allred8(HF1r * m);   // (HF m)[1]
        float mn = matvec8(Fd, m);            // (F m)[r]
        m = fmaf(fk0, y0, fmaf(fk1, y1, mn)); // m' = F m + FK y
        mm0 = fmaf(hfk00, y0, fmaf(hfk01, y1, wa));  // mm' = HF m + HFK y
        mm1 = fmaf(hfk10, y0, fmaf(hfk11, y1, wb));
      }
      if (r == 0) {
        *reinterpret_cast<float4*>(mo + 2 * tb)     = make_float4(b0.x, b0.y, b1.x, b1.y);
        *reinterpret_cast<float4*>(mo + 2 * tb + 4) = make_float4(b2.x, b2.y, b3.x, b3.y);
      }
      xa = na; xb = nb;
      int tf = tb + 8; if (tf > NT - 4) tf = NT - 4;
      na = *reinterpret_cast<const float4*>(xg + 2 * tf);
      nb = *reinterpret_cast<const float4*>(xg + 2 * tf + 4);
    }
  }
}

extern "C" void kernel_launch(void* const* d_in, const int* in_sizes, int n_in,
                              void* d_out, int out_size, void* d_ws, size_t ws_size,
                              hipStream_t stream) {
  const float* x  = (const float*)d_in[0];
  const float* m0 = (const float*)d_in[1];
  const float* P0 = (const float*)d_in[2];
  const float* F  = (const float*)d_in[3];
  const float* Q  = (const float*)d_in[4];
  const float* H  = (const float*)d_in[5];
  const float* R  = (const float*)d_in[6];
  float* out = (float*)d_out;

  dim3 grid(NG * 8 / 256), block(256);
  hipLaunchKernelGGL(kf_kernel, grid, block, 0, stream,
                     x, m0, P0, F, Q, H, R, out);
}